// Round 5
// baseline (209.019 us; speedup 1.0000x reference)
//
#include <hip/hip_runtime.h>
#include <hip/hip_bf16.h>
#include <stdint.h>

// Problem constants
#define B_M 512
#define D_K 512
#define C_N 100000
#define BN_OUT 100   // columns stored per pid (compute tile stays 128 wide)
#define N_PID 1000   // N_PID * BN_OUT == C_N exactly
#define S_SCALE 64.0f
#define W_LOSS 0.003f
#define COS_M_C 0.79608379854905604f
#define SIN_M_C 0.60518640573603957f
#define THRESH_C (-0.79608379854905604f)
#define MM_C 0.39337116372842573f

typedef __bf16 bf16x8 __attribute__((ext_vector_type(8)));
typedef float f32x4 __attribute__((ext_vector_type(4)));

typedef const __attribute__((address_space(1))) unsigned char* gptr_t;
typedef __attribute__((address_space(3))) unsigned char* sptr_t;

__device__ __forceinline__ unsigned short f2bf(float f) {
  __bf16 h = (__bf16)f;
  return __builtin_bit_cast(unsigned short, h);
}

// ---------------------------------------------------------------------------
// Kernel 1: normalize emb rows (f32), write swizzled bf16 A-tiles to ws,
// compute target_logit[b] exactly in f32.
// wsA layout: 16 tiles (mhalf 0..1  x  ktile 0..7) of 32 KB;
// tile = [256 rows][128 B], byte-in-row XOR ((row&7)<<4)  (LDS image).
// ---------------------------------------------------------------------------
__global__ __launch_bounds__(256) void prep_kernel(
    const float* __restrict__ emb, const float* __restrict__ Kg,
    const int* __restrict__ label, unsigned char* __restrict__ wsA,
    float* __restrict__ tl)
{
  int b = blockIdx.x, t = threadIdx.x;
  __shared__ float row[512];
  __shared__ float r1[256], r2[256];

  float2 v = ((const float2*)(emb + (size_t)b * 512))[t];
  r1[t] = v.x * v.x + v.y * v.y;
  __syncthreads();
  for (int s = 128; s > 0; s >>= 1) {
    if (t < s) r1[t] += r1[t + s];
    __syncthreads();
  }
  float inv = 1.0f / sqrtf(r1[0]);
  float e0 = v.x * inv, e1 = v.y * inv;
  row[2 * t] = e0;
  row[2 * t + 1] = e1;

  {
    int mhalf = b >> 8, lrow = b & 255;
    int kk = t >> 5;  // (2t)/64 : k-tile index
    int byte_in = (4 * (t & 31)) ^ ((lrow & 7) << 4);
    ushort2 h;
    h.x = f2bf(e0);
    h.y = f2bf(e1);
    *(ushort2*)(wsA + (size_t)(mhalf * 8 + kk) * 32768 + lrow * 128 + byte_in) = h;
  }
  __syncthreads();

  int lab = label[b];
  const float* kc = Kg + lab;
  float dot = 0.f, csq = 0.f;
  for (int d = t; d < 512; d += 256) {
    float kv = kc[(size_t)d * C_N];
    dot += row[d] * kv;
    csq += kv * kv;
  }
  r1[t] = dot;
  r2[t] = csq;
  __syncthreads();
  for (int s = 128; s > 0; s >>= 1) {
    if (t < s) { r1[t] += r1[t + s]; r2[t] += r2[t + s]; }
    __syncthreads();
  }
  if (t == 0) {
    float tlv = r1[0] / sqrtf(r2[0]);
    tl[b] = fminf(1.f, fmaxf(-1.f, tlv));
  }
}

// ---------------------------------------------------------------------------
// Kernel 2: fused GEMM + epilogue (finalize folded in).
// Compute tile BM=256 x 128 cols, BK=64; only cols [0,100) stored ->
// grid = 2 mhalf x 1000 pids = 2000 tiles (91%-full last cohort vs 5%).
// Pipeline: A dbuf LDS (gll 1 ahead), B 2-ahead in regs, counted vmcnt(16).
// Epilogue: tnew/ctm/ftl recomputed per block from tl[] (L2-hot);
// acc -> LDS -> 400B-contiguous NT stores.
// ---------------------------------------------------------------------------
#define LDS_TOTAL 81920  // A dbuf: 2*32768 @ [0,65536); B: 16384 @ [65536,81920)

__global__ __launch_bounds__(512, 2) void gemm_kernel(
    const float* __restrict__ Kg, const unsigned char* __restrict__ wsA,
    const float* __restrict__ tl_g, const float* __restrict__ t_in_g,
    const int* __restrict__ label,
    float* __restrict__ out1, float* __restrict__ out2,
    float* __restrict__ out3)
{
  __shared__ __align__(16) unsigned char smem[LDS_TOTAL];

  int t = threadIdx.x;
  int lane = t & 63, wv = t >> 6;
  int wm = wv >> 2, wn = wv & 3;  // 2M x 4N
  bool orig0 = (blockIdx.x == 0);

  // m204 bijective XCD swizzle: nwg=2000, q=250, r=0 -> swz = xcd*250 + seq.
  // mhalf pair (2p,2p+1) lands contiguous on one XCD -> B panel L2 reuse;
  // neighboring pids also contiguous -> 28-col panel overlap is L2-hot.
  int bid = blockIdx.x;
  {
    int xcd = bid & 7, seq = bid >> 3;
    bid = xcd * 250 + seq;
  }
  int pid = bid >> 1, mhalf = bid & 1;
  long c0 = (long)pid * BN_OUT;

  // B staging: thread owns column c (t&127), k-segment kseg (t>>7): 16 k's
  int c = t & 127, kseg = t >> 7;
  bool binb = (c0 + c) < C_N;
  const float* Bcol = Kg + c0 + c + (size_t)kseg * 16 * C_N;

  f32x4 acc[8][2] = {};
  float csq = 0.f;
  float bf0[16], bf1[16];  // B[j] lives in set (j&1)

  const unsigned char* wsTile = wsA + (size_t)mhalf * (8 * 32768);
  unsigned char* smemB = smem + 65536;
  unsigned char* browB = smemB + c * 128;

#define LOAD_B(dst, j)                                                       \
  {                                                                          \
    const float* src = Bcol + (size_t)((j) * 64) * C_N;                      \
    _Pragma("unroll") for (int i = 0; i < 16; ++i)                           \
        dst[i] = binb ? src[(size_t)i * C_N] : 0.f;                          \
  }

#define WRITE_B(src)                                                         \
  {                                                                          \
    _Pragma("unroll") for (int i = 0; i < 16; ++i) csq += src[i] * src[i];   \
    union { unsigned short u[16]; uint4 q[2]; } pk;                          \
    _Pragma("unroll") for (int i = 0; i < 16; ++i) pk.u[i] = f2bf(src[i]);   \
    _Pragma("unroll") for (int h = 0; h < 2; ++h)                            \
      *(uint4*)(browB + ((kseg * 32 + h * 16) ^ ((c & 7) << 4))) = pk.q[h];  \
  }

  // ---- prologue: A[0] DMA, B[0]/B[1] reg loads, B[0] -> LDS
  {
#pragma unroll
    for (int i = 0; i < 4; ++i) {
      int off = wv * 4096 + i * 1024;
      __builtin_amdgcn_global_load_lds((gptr_t)(wsTile + off + lane * 16),
                                       (sptr_t)(smem + off), 16, 0, 0);
    }
    __builtin_amdgcn_sched_barrier(0);
    LOAD_B(bf0, 0);
    __builtin_amdgcn_sched_barrier(0);
    LOAD_B(bf1, 1);
    __builtin_amdgcn_sched_barrier(0);
    asm volatile("s_waitcnt vmcnt(16)" ::: "memory");  // A[0]+B[0] done
    __builtin_amdgcn_sched_barrier(0);
    WRITE_B(bf0);
    __syncthreads();
  }

  // ---- main loop: 8 K-steps, fully unrolled (static reg-set selects)
#pragma unroll
  for (int kkt = 0; kkt < 8; ++kkt) {
    int cur = kkt & 1;
    if (kkt < 7) {
      const unsigned char* tA = wsTile + (size_t)(kkt + 1) * 32768;
#pragma unroll
      for (int i = 0; i < 4; ++i) {
        int off = wv * 4096 + i * 1024;
        __builtin_amdgcn_global_load_lds((gptr_t)(tA + off + lane * 16),
                                         (sptr_t)(smem + (cur ^ 1) * 32768 + off), 16, 0, 0);
      }
      __builtin_amdgcn_sched_barrier(0);
    }
    if (kkt < 6) {
      if (kkt & 1) { LOAD_B(bf1, kkt + 2); } else { LOAD_B(bf0, kkt + 2); }
      __builtin_amdgcn_sched_barrier(0);
    }

    // compute current buffers
    const unsigned char* Ab = smem + cur * 32768;
#pragma unroll
    for (int ks = 0; ks < 2; ++ks) {
      int kb = ks * 64 + (lane >> 4) * 16;
      bf16x8 bfr[2];
#pragma unroll
      for (int nf = 0; nf < 2; ++nf) {
        int n = wn * 32 + nf * 16 + (lane & 15);
        bfr[nf] = *(const bf16x8*)(smemB + n * 128 + (kb ^ ((n & 7) << 4)));
      }
#pragma unroll
      for (int mf = 0; mf < 8; ++mf) {
        int m = wm * 128 + mf * 16 + (lane & 15);
        bf16x8 afr = *(const bf16x8*)(Ab + m * 128 + (kb ^ ((m & 7) << 4)));
        acc[mf][0] = __builtin_amdgcn_mfma_f32_16x16x32_bf16(afr, bfr[0], acc[mf][0], 0, 0, 0);
        acc[mf][1] = __builtin_amdgcn_mfma_f32_16x16x32_bf16(afr, bfr[1], acc[mf][1], 0, 0, 0);
      }
    }

    // counted wait: retire {B[k+1] regs (16), A[k+1] DMA (4)}, keep B[k+2]
    // (16 newest) in flight across the barrier. Last steps drain fully.
    if (kkt < 6) {
      asm volatile("s_waitcnt vmcnt(16)" ::: "memory");
    } else {
      asm volatile("s_waitcnt vmcnt(0)" ::: "memory");
    }
    __builtin_amdgcn_sched_barrier(0);
    __syncthreads();  // barrier-1: B-LDS reads done, A[k+1] landed

    if (kkt < 7) {
      if (kkt & 1) { WRITE_B(bf0); } else { WRITE_B(bf1); }
      __syncthreads();  // barrier-2: B[k+1] visible
    }
  }

  // ---- finalize fold + column norms (alias B region; all buffers dead)
  float* red1    = (float*)(smemB);         // [512]
  float* red2    = (float*)(smemB + 2048);  // [512]
  float* colpart = (float*)(smemB + 4096);  // [512]
  float* invn    = (float*)(smemB + 6144);  // [128]
  float* ctm_s   = (float*)(smemB + 6656);  // [256]
  float* ftl_s   = (float*)(smemB + 7680);  // [256]
  int*   lab_s   = (int*)  (smemB + 8704);  // [256]

  float tlv = tl_g[t];
  float acv = acosf(tlv);
  red1[t] = tlv;
  red2[t] = acv * sqrtf(acv);  // acos^1.5
  colpart[t] = csq;
  if (t < 256) lab_s[t] = label[mhalf * 256 + t];
  __syncthreads();
  if (t < 128) {
    float s = colpart[t] + colpart[t + 128] + colpart[t + 256] + colpart[t + 384];
    invn[t] = 1.0f / sqrtf(fmaxf(s, 1e-30f));
  } else if (t >= 256) {
    int r = t - 256;
    float v2 = tl_g[mhalf * 256 + r];
    float st = sqrtf(fmaxf(0.f, 1.f - v2 * v2));
    float cm = v2 * COS_M_C - st * SIN_M_C;
    ctm_s[r] = cm;
    ftl_s[r] = (v2 > THRESH_C) ? cm : (v2 - MM_C);
  }
  for (int s = 256; s > 0; s >>= 1) {
    __syncthreads();
    if (t < s) { red1[t] += red1[t + s]; red2[t] += red2[t + s]; }
  }
  __syncthreads();
  float tn = 0.99f * t_in_g[0] + 0.01f * (red1[0] * (1.0f / 512.0f));
  if (orig0 && t == 0) out3[0] = S_SCALE * W_LOSS * (red2[0] * (1.0f / 512.0f));
  __syncthreads();

  // ---- epilogue: 2 chunks of 128 rows; stage acc in LDS, stream 400B rows
  for (int q = 0; q < 2; ++q) {
    if (wm == q) {
#pragma unroll
      for (int mf = 0; mf < 8; ++mf) {
#pragma unroll
        for (int nf = 0; nf < 2; ++nf) {
#pragma unroll
          for (int j = 0; j < 4; ++j) {
            int row = mf * 16 + (lane >> 4) * 4 + j;
            int col = wn * 32 + nf * 16 + (lane & 15);
            *(float*)(smem + row * 512 + ((col * 4) ^ (((row >> 2) & 3) << 6))) =
                acc[mf][nf][j];
          }
        }
      }
    }
    __syncthreads();
#pragma unroll
    for (int rr = 0; rr < 8; ++rr) {
      int row = rr * 16 + (t >> 5);
      int cb = (t & 31) * 4;
      f32x4 v = *(const f32x4*)(smem + row * 512 + ((cb * 4) ^ (((row >> 2) & 3) << 6)));
      if (cb < BN_OUT) {  // cols [0,100) stored; c0+cb <= 99996 always in-range
        long cgs = c0 + cb;
        int lrow = q * 128 + row;
        float cm = ctm_s[lrow], fl = ftl_s[lrow];
        int lb = lab_s[lrow];
        f32x4 iv = *(const f32x4*)(invn + cb);
        f32x4 o1v, o2v;
#pragma unroll
        for (int jj = 0; jj < 4; ++jj) {
          float cosv = fminf(1.f, fmaxf(-1.f, v[jj] * iv[jj]));
          o2v[jj] = cosv * S_SCALE;
          float ct = (cosv > cm) ? cosv * (tn + cosv) : cosv;
          if (lb == (int)(cgs + jj)) ct = fl;
          o1v[jj] = ct * S_SCALE;
        }
        size_t idx = (size_t)(mhalf * 256 + lrow) * C_N + cgs;
        __builtin_nontemporal_store(o1v, (f32x4*)(out1 + idx));
        __builtin_nontemporal_store(o2v, (f32x4*)(out2 + idx));
      }
    }
    __syncthreads();
  }
#undef LOAD_B
#undef WRITE_B
}

// ---------------------------------------------------------------------------
extern "C" void kernel_launch(void* const* d_in, const int* in_sizes, int n_in,
                              void* d_out, int out_size, void* d_ws, size_t ws_size,
                              hipStream_t stream)
{
  const float* emb   = (const float*)d_in[0];
  const float* Kg    = (const float*)d_in[1];
  const float* t_in  = (const float*)d_in[2];
  const int*   label = (const int*)d_in[3];

  float* out1 = (float*)d_out;                 // output * S   [512*100000]
  float* out2 = out1 + (size_t)B_M * C_N;      // origin * S   [512*100000]
  float* out3 = out1 + 2 * (size_t)B_M * C_N;  // scalar loss

  unsigned char* wsA = (unsigned char*)d_ws;   // 512KB swizzled bf16 A tiles
  float* tl = (float*)((unsigned char*)d_ws + 524288);

  prep_kernel<<<512, 256, 0, stream>>>(emb, Kg, label, wsA, tl);
  gemm_kernel<<<2 * N_PID, 512, 0, stream>>>(Kg, wsA, tl, t_in, label,
                                             out1, out2, out3);
}